// Round 1
// baseline (248.594 us; speedup 1.0000x reference)
//
#include <hip/hip_runtime.h>
#include <stdint.h>

#define EPS 1e-5f

typedef float f32x4 __attribute__((ext_vector_type(4)));
typedef __bf16 bf16x8 __attribute__((ext_vector_type(8)));

__device__ __forceinline__ ushort f2bf(float f){
  union { float f; uint32_t u; } v; v.f = f;
  uint32_t r = v.u + 0x7fffu + ((v.u >> 16) & 1u);
  return (ushort)(r >> 16);
}

__device__ __forceinline__ f32x4 mfma16(bf16x8 a, bf16x8 b, f32x4 c){
  return __builtin_amdgcn_mfma_f32_16x16x32_bf16(a, b, c, 0, 0, 0);
}

// ---------------- prep: weights f32 -> bf16 ----------------
__global__ __launch_bounds__(256) void k_prep(const float* wq, const float* wp,
                                              ushort* wqb, ushort* wpb){
  int i = blockIdx.x * 256 + threadIdx.x;
  if (i < 3*256*256) wqb[i] = f2bf(wq[i]);
  if (i < 256*256)   wpb[i] = f2bf(wp[i]);
}

// ---------------- groupnorm stats stage 1 ----------------
// grid: 16 (b,g) * 64 partial blocks; each block sums 2048 floats
__global__ __launch_bounds__(256) void k_gn1(const float* x, float2* part){
  int bg = blockIdx.x >> 6, pb = blockIdx.x & 63;
  const f32x4* base = (const f32x4*)(x + (size_t)bg*131072 + (size_t)pb*2048);
  float s = 0.f, ss = 0.f;
  #pragma unroll
  for (int it = 0; it < 2; ++it){
    f32x4 v = base[threadIdx.x + it*256];
    #pragma unroll
    for (int j = 0; j < 4; ++j){ s += v[j]; ss += v[j]*v[j]; }
  }
  #pragma unroll
  for (int off = 1; off < 64; off <<= 1){
    s  += __shfl_xor(s,  off);
    ss += __shfl_xor(ss, off);
  }
  __shared__ float red[8];
  int wid = threadIdx.x >> 6;
  if ((threadIdx.x & 63) == 0){ red[wid] = s; red[4 + wid] = ss; }
  __syncthreads();
  if (threadIdx.x == 0){
    part[blockIdx.x] = make_float2(red[0]+red[1]+red[2]+red[3],
                                   red[4]+red[5]+red[6]+red[7]);
  }
}

// ---------------- groupnorm stats stage 2 ----------------
// grid: 16 blocks x 64 threads
__global__ __launch_bounds__(64) void k_gn2(const float2* part, float2* stats){
  int bg = blockIdx.x;
  float2 p = part[bg*64 + threadIdx.x];
  float s = p.x, ss = p.y;
  #pragma unroll
  for (int off = 1; off < 64; off <<= 1){
    s  += __shfl_xor(s,  off);
    ss += __shfl_xor(ss, off);
  }
  if (threadIdx.x == 0){
    const float inv = 1.f / 131072.f;
    float mean = s * inv;
    float var  = ss * inv - mean*mean;
    stats[bg] = make_float2(mean, rsqrtf(var + EPS));
  }
}

// ---------------- fused GN-normalize + QKV GEMM ----------------
// out^T[n][o] = xn^T[n][c] * W^T[c][o];  A staged in LDS (normalized, transposed),
// B fragments read directly from bf16 W rows (contiguous K).
// grid: (64 ntiles, 12 otiles, 2 b) x 256
__global__ __launch_bounds__(256) void k_qkv(const float* x, const float* gamma, const float* beta,
                                             const float2* stats, const ushort* wqb, const float* bqkv,
                                             ushort* Qb, ushort* Kb, ushort* Vb){
  __shared__ ushort A[64][264];   // [n][c], pad 8
  int b = blockIdx.z, ot = blockIdx.y, nt = blockIdx.x;
  int t = threadIdx.x;
  int nlane = t & 15, cpair = t >> 4;
  int nbase = nt * 64;

  #pragma unroll
  for (int it = 0; it < 8; ++it){
    int c = cpair*2 + it*32;
    float2 st = stats[b*8 + (c >> 5)];
    f32x4 v0 = *(const f32x4*)(x + ((size_t)(b*256 + c    ))*4096 + nbase + nlane*4);
    f32x4 v1 = *(const f32x4*)(x + ((size_t)(b*256 + c + 1))*4096 + nbase + nlane*4);
    float g0 = gamma[c], b0 = beta[c], g1 = gamma[c+1], b1 = beta[c+1];
    #pragma unroll
    for (int j = 0; j < 4; ++j){
      uint32_t lo = f2bf((v0[j] - st.x) * st.y * g0 + b0);
      uint32_t hi = f2bf((v1[j] - st.x) * st.y * g1 + b1);
      *(uint32_t*)&A[nlane*4 + j][c] = lo | (hi << 16);
    }
  }
  __syncthreads();

  int lane = t & 63, wid = t >> 6, l15 = lane & 15, g4 = lane >> 4;
  int o = ot*64 + wid*16 + l15;
  f32x4 acc[4];
  #pragma unroll
  for (int m = 0; m < 4; ++m) acc[m] = (f32x4){0.f,0.f,0.f,0.f};

  #pragma unroll
  for (int ks = 0; ks < 8; ++ks){
    bf16x8 bw = *(const bf16x8*)(wqb + (size_t)o*256 + ks*32 + g4*8);
    #pragma unroll
    for (int mf = 0; mf < 4; ++mf){
      bf16x8 aa = *(const bf16x8*)&A[mf*16 + l15][ks*32 + g4*8];
      acc[mf] = mfma16(aa, bw, acc[mf]);
    }
  }

  int tt = o >> 8, h = (o >> 6) & 3, d = o & 63;
  int bh = b*4 + h;
  float bias = bqkv[o];
  if (tt == 2){
    ushort* dst = Vb + ((size_t)bh*64 + d)*4096;
    #pragma unroll
    for (int mf = 0; mf < 4; ++mf){
      int n0 = nbase + mf*16 + g4*4;
      uint32_t w0 = (uint32_t)f2bf(acc[mf][0]+bias) | ((uint32_t)f2bf(acc[mf][1]+bias) << 16);
      uint32_t w1 = (uint32_t)f2bf(acc[mf][2]+bias) | ((uint32_t)f2bf(acc[mf][3]+bias) << 16);
      *(uint2*)(dst + n0) = make_uint2(w0, w1);
    }
  } else {
    ushort* dst = (tt == 0 ? Qb : Kb) + (size_t)bh*4096*64 + d;
    #pragma unroll
    for (int mf = 0; mf < 4; ++mf){
      int n0 = nbase + mf*16 + g4*4;
      #pragma unroll
      for (int r = 0; r < 4; ++r) dst[(size_t)(n0 + r)*64] = f2bf(acc[mf][r] + bias);
    }
  }
}

// ---------------- flash attention ----------------
// grid: (64 qtiles, 4 heads, 2 b) x 256 (4 waves x 16 q-rows)
__global__ __launch_bounds__(256) void k_attn(const ushort* Qb, const ushort* Kb,
                                              const ushort* Vb, ushort* AO){
  __shared__ ushort Kl[64][72];
  __shared__ ushort Vl[64][72];
  __shared__ ushort Pl[4][16][72];
  int qt = blockIdx.x, h = blockIdx.y, b = blockIdx.z;
  int bh = b*4 + h;
  int t = threadIdx.x, lane = t & 63, wid = t >> 6, l15 = lane & 15, g4 = lane >> 4;

  const ushort* Qg = Qb + ((size_t)bh*4096 + qt*64 + wid*16 + l15)*64 + g4*8;
  bf16x8 aq0 = *(const bf16x8*)Qg;
  bf16x8 aq1 = *(const bf16x8*)(Qg + 32);

  f32x4 oacc[4];
  #pragma unroll
  for (int m = 0; m < 4; ++m) oacc[m] = (f32x4){0.f,0.f,0.f,0.f};
  float m_r[4], l_r[4];
  #pragma unroll
  for (int r = 0; r < 4; ++r){ m_r[r] = -INFINITY; l_r[r] = 0.f; }

  const ushort* Kgb = Kb + (size_t)bh*4096*64;
  const ushort* Vgb = Vb + (size_t)bh*64*4096;

  for (int kb = 0; kb < 64; ++kb){
    #pragma unroll
    for (int it = 0; it < 2; ++it){
      int idx = t + it*256;
      int row = idx >> 3, seg = (idx & 7)*8;
      *(bf16x8*)&Kl[row][seg] = *(const bf16x8*)(Kgb + (size_t)(kb*64 + row)*64 + seg);
      *(bf16x8*)&Vl[row][seg] = *(const bf16x8*)(Vgb + (size_t)row*4096 + kb*64 + seg);
    }
    __syncthreads();

    f32x4 s[4];
    #pragma unroll
    for (int m = 0; m < 4; ++m) s[m] = (f32x4){0.f,0.f,0.f,0.f};
    #pragma unroll
    for (int ks = 0; ks < 2; ++ks){
      bf16x8 a = ks ? aq1 : aq0;
      #pragma unroll
      for (int ct = 0; ct < 4; ++ct){
        bf16x8 kf = *(const bf16x8*)&Kl[ct*16 + l15][ks*32 + g4*8];
        s[ct] = mfma16(a, kf, s[ct]);
      }
    }

    float p[4][4];
    #pragma unroll
    for (int r = 0; r < 4; ++r){
      float v = fmaxf(fmaxf(s[0][r], s[1][r]), fmaxf(s[2][r], s[3][r]));
      v = fmaxf(v, __shfl_xor(v, 1));
      v = fmaxf(v, __shfl_xor(v, 2));
      v = fmaxf(v, __shfl_xor(v, 4));
      v = fmaxf(v, __shfl_xor(v, 8));
      float mn = fmaxf(m_r[r], v * 0.125f);
      float a = __expf(m_r[r] - mn);
      float rs = 0.f;
      #pragma unroll
      for (int ct = 0; ct < 4; ++ct){ p[ct][r] = __expf(s[ct][r]*0.125f - mn); rs += p[ct][r]; }
      rs += __shfl_xor(rs, 1); rs += __shfl_xor(rs, 2);
      rs += __shfl_xor(rs, 4); rs += __shfl_xor(rs, 8);
      l_r[r] = l_r[r]*a + rs;
      m_r[r] = mn;
      #pragma unroll
      for (int dt = 0; dt < 4; ++dt) oacc[dt][r] *= a;
    }

    #pragma unroll
    for (int ct = 0; ct < 4; ++ct)
      #pragma unroll
      for (int r = 0; r < 4; ++r)
        Pl[wid][g4*4 + r][ct*16 + l15] = f2bf(p[ct][r]);
    __syncthreads();

    #pragma unroll
    for (int ks = 0; ks < 2; ++ks){
      bf16x8 pf = *(const bf16x8*)&Pl[wid][l15][ks*32 + g4*8];
      #pragma unroll
      for (int dt = 0; dt < 4; ++dt){
        bf16x8 vf = *(const bf16x8*)&Vl[dt*16 + l15][ks*32 + g4*8];
        oacc[dt] = mfma16(pf, vf, oacc[dt]);
      }
    }
    __syncthreads();
  }

  #pragma unroll
  for (int r = 0; r < 4; ++r){
    float inv = 1.f / l_r[r];
    int n = qt*64 + wid*16 + g4*4 + r;
    ushort* dst = AO + ((size_t)b*4096 + n)*256 + h*64;
    #pragma unroll
    for (int dt = 0; dt < 4; ++dt)
      dst[dt*16 + l15] = f2bf(oacc[dt][r] * inv);
  }
}

// ---------------- proj GEMM + bias + residual ----------------
// y[b][co][n] = w_proj[co][ci] * AO^T + b + x;  A frags straight from AO rows.
// grid: (64 ntiles, 4 cotiles, 2 b) x 256
__global__ __launch_bounds__(256) void k_proj(const ushort* AO, const ushort* wpb, const float* bproj,
                                              const float* x, float* out){
  int nt = blockIdx.x, ct = blockIdx.y, b = blockIdx.z;
  int t = threadIdx.x, lane = t & 63, wid = t >> 6, l15 = lane & 15, g4 = lane >> 4;
  int o = ct*64 + wid*16 + l15;
  f32x4 acc[4];
  #pragma unroll
  for (int m = 0; m < 4; ++m) acc[m] = (f32x4){0.f,0.f,0.f,0.f};

  #pragma unroll
  for (int ks = 0; ks < 8; ++ks){
    bf16x8 bw = *(const bf16x8*)(wpb + (size_t)o*256 + ks*32 + g4*8);
    #pragma unroll
    for (int mf = 0; mf < 4; ++mf){
      int n = nt*64 + mf*16 + l15;
      bf16x8 aa = *(const bf16x8*)(AO + ((size_t)b*4096 + n)*256 + ks*32 + g4*8);
      acc[mf] = mfma16(aa, bw, acc[mf]);
    }
  }

  float bias = bproj[o];
  size_t cbase = ((size_t)b*256 + o)*4096;
  #pragma unroll
  for (int mf = 0; mf < 4; ++mf){
    int n0 = nt*64 + mf*16 + g4*4;
    f32x4 res = *(const f32x4*)(x + cbase + n0);
    f32x4 ov;
    #pragma unroll
    for (int r = 0; r < 4; ++r) ov[r] = acc[mf][r] + bias + res[r];
    *(f32x4*)(out + cbase + n0) = ov;
  }
}

extern "C" void kernel_launch(void* const* d_in, const int* in_sizes, int n_in,
                              void* d_out, int out_size, void* d_ws, size_t ws_size,
                              hipStream_t stream) {
  const float* x     = (const float*)d_in[0];
  const float* gamma = (const float*)d_in[1];
  const float* beta  = (const float*)d_in[2];
  const float* wqkv  = (const float*)d_in[3];
  const float* bqkv  = (const float*)d_in[4];
  const float* wproj = (const float*)d_in[5];
  const float* bproj = (const float*)d_in[6];
  float* out = (float*)d_out;

  char* ws = (char*)d_ws;
  float2* part   = (float2*)(ws + 0);          // 8 KB
  float2* stats  = (float2*)(ws + 8192);       // 128 B
  ushort* wq_b   = (ushort*)(ws + 16384);      // 384 KB
  ushort* wp_b   = (ushort*)(ws + 409600);     // 128 KB
  ushort* Qb     = (ushort*)(ws + 1048576);    // 4 MB  [bh][n][d]
  ushort* Kb     = (ushort*)(ws + 5242880);    // 4 MB  [bh][n][d]
  ushort* Vb     = (ushort*)(ws + 9437184);    // 4 MB  [bh][d][n]
  ushort* AO     = (ushort*)(ws + 13631488);   // 4 MB  [b][n][ci]

  k_prep<<<768, 256, 0, stream>>>(wqkv, wproj, wq_b, wp_b);
  k_gn1 <<<1024, 256, 0, stream>>>(x, part);
  k_gn2 <<<16, 64, 0, stream>>>(part, stats);
  k_qkv <<<dim3(64,12,2), 256, 0, stream>>>(x, gamma, beta, stats, wq_b, bqkv, Qb, Kb, Vb);
  k_attn<<<dim3(64,4,2), 256, 0, stream>>>(Qb, Kb, Vb, AO);
  k_proj<<<dim3(64,4,2), 256, 0, stream>>>(AO, wp_b, bproj, x, out);
}

// Round 2
// 185.715 us; speedup vs baseline: 1.3386x; 1.3386x over previous
//
#include <hip/hip_runtime.h>
#include <stdint.h>

#define EPS 1e-5f

typedef float f32x4 __attribute__((ext_vector_type(4)));
typedef __bf16 bf16x8 __attribute__((ext_vector_type(8)));

__device__ __forceinline__ ushort f2bf(float f){
  union { float f; uint32_t u; } v; v.f = f;
  uint32_t r = v.u + 0x7fffu + ((v.u >> 16) & 1u);
  return (ushort)(r >> 16);
}

__device__ __forceinline__ uint32_t pk2bf(float a, float b){
  __bf16 x = (__bf16)a, y = (__bf16)b;
  return (uint32_t)__builtin_bit_cast(ushort, x) |
         ((uint32_t)__builtin_bit_cast(ushort, y) << 16);
}

__device__ __forceinline__ f32x4 mfma16(bf16x8 a, bf16x8 b, f32x4 c){
  return __builtin_amdgcn_mfma_f32_16x16x32_bf16(a, b, c, 0, 0, 0);
}

// ---------------- prep: weights f32 -> bf16 ----------------
__global__ __launch_bounds__(256) void k_prep(const float* wq, const float* wp,
                                              ushort* wqb, ushort* wpb){
  int i = blockIdx.x * 256 + threadIdx.x;
  if (i < 3*256*256) wqb[i] = f2bf(wq[i]);
  if (i < 256*256)   wpb[i] = f2bf(wp[i]);
}

// ---------------- groupnorm stats stage 1 ----------------
__global__ __launch_bounds__(256) void k_gn1(const float* x, float2* part){
  int bg = blockIdx.x >> 6, pb = blockIdx.x & 63;
  const f32x4* base = (const f32x4*)(x + (size_t)bg*131072 + (size_t)pb*2048);
  float s = 0.f, ss = 0.f;
  #pragma unroll
  for (int it = 0; it < 2; ++it){
    f32x4 v = base[threadIdx.x + it*256];
    #pragma unroll
    for (int j = 0; j < 4; ++j){ s += v[j]; ss += v[j]*v[j]; }
  }
  #pragma unroll
  for (int off = 1; off < 64; off <<= 1){
    s  += __shfl_xor(s,  off);
    ss += __shfl_xor(ss, off);
  }
  __shared__ float red[8];
  int wid = threadIdx.x >> 6;
  if ((threadIdx.x & 63) == 0){ red[wid] = s; red[4 + wid] = ss; }
  __syncthreads();
  if (threadIdx.x == 0){
    part[blockIdx.x] = make_float2(red[0]+red[1]+red[2]+red[3],
                                   red[4]+red[5]+red[6]+red[7]);
  }
}

// ---------------- groupnorm stats stage 2 ----------------
__global__ __launch_bounds__(64) void k_gn2(const float2* part, float2* stats){
  int bg = blockIdx.x;
  float2 p = part[bg*64 + threadIdx.x];
  float s = p.x, ss = p.y;
  #pragma unroll
  for (int off = 1; off < 64; off <<= 1){
    s  += __shfl_xor(s,  off);
    ss += __shfl_xor(ss, off);
  }
  if (threadIdx.x == 0){
    const float inv = 1.f / 131072.f;
    float mean = s * inv;
    float var  = ss * inv - mean*mean;
    stats[bg] = make_float2(mean, rsqrtf(var + EPS));
  }
}

// ---------------- fused GN-normalize + QKV GEMM ----------------
__global__ __launch_bounds__(256) void k_qkv(const float* x, const float* gamma, const float* beta,
                                             const float2* stats, const ushort* wqb, const float* bqkv,
                                             ushort* Qb, ushort* Kb, ushort* Vb){
  __shared__ ushort A[64][264];   // [n][c], pad 8
  int b = blockIdx.z, ot = blockIdx.y, nt = blockIdx.x;
  int t = threadIdx.x;
  int nlane = t & 15, cpair = t >> 4;
  int nbase = nt * 64;

  #pragma unroll
  for (int it = 0; it < 8; ++it){
    int c = cpair*2 + it*32;
    float2 st = stats[b*8 + (c >> 5)];
    f32x4 v0 = *(const f32x4*)(x + ((size_t)(b*256 + c    ))*4096 + nbase + nlane*4);
    f32x4 v1 = *(const f32x4*)(x + ((size_t)(b*256 + c + 1))*4096 + nbase + nlane*4);
    float g0 = gamma[c], b0 = beta[c], g1 = gamma[c+1], b1 = beta[c+1];
    #pragma unroll
    for (int j = 0; j < 4; ++j){
      uint32_t lo = f2bf((v0[j] - st.x) * st.y * g0 + b0);
      uint32_t hi = f2bf((v1[j] - st.x) * st.y * g1 + b1);
      *(uint32_t*)&A[nlane*4 + j][c] = lo | (hi << 16);
    }
  }
  __syncthreads();

  int lane = t & 63, wid = t >> 6, l15 = lane & 15, g4 = lane >> 4;
  int o = ot*64 + wid*16 + l15;
  f32x4 acc[4];
  #pragma unroll
  for (int m = 0; m < 4; ++m) acc[m] = (f32x4){0.f,0.f,0.f,0.f};

  #pragma unroll
  for (int ks = 0; ks < 8; ++ks){
    bf16x8 bw = *(const bf16x8*)(wqb + (size_t)o*256 + ks*32 + g4*8);
    #pragma unroll
    for (int mf = 0; mf < 4; ++mf){
      bf16x8 aa = *(const bf16x8*)&A[mf*16 + l15][ks*32 + g4*8];
      acc[mf] = mfma16(aa, bw, acc[mf]);
    }
  }

  int tt = o >> 8, h = (o >> 6) & 3, d = o & 63;
  int bh = b*4 + h;
  float bias = bqkv[o];
  if (tt == 2){
    ushort* dst = Vb + ((size_t)bh*64 + d)*4096;
    #pragma unroll
    for (int mf = 0; mf < 4; ++mf){
      int n0 = nbase + mf*16 + g4*4;
      uint32_t w0 = (uint32_t)f2bf(acc[mf][0]+bias) | ((uint32_t)f2bf(acc[mf][1]+bias) << 16);
      uint32_t w1 = (uint32_t)f2bf(acc[mf][2]+bias) | ((uint32_t)f2bf(acc[mf][3]+bias) << 16);
      *(uint2*)(dst + n0) = make_uint2(w0, w1);
    }
  } else {
    ushort* dst = (tt == 0 ? Qb : Kb) + (size_t)bh*4096*64 + d;
    #pragma unroll
    for (int mf = 0; mf < 4; ++mf){
      int n0 = nbase + mf*16 + g4*4;
      #pragma unroll
      for (int r = 0; r < 4; ++r) dst[(size_t)(n0 + r)*64] = f2bf(acc[mf][r] + bias);
    }
  }
}

// ---------------- flash attention v2 ----------------
// swapped QK^T (S^T = K·Q^T) -> lane-local softmax rows; dbuf K/V; 1 barrier/iter.
// grid: (64 qtiles, 4 heads, 2 b) x 256 (4 waves x 16 q-rows)
__global__ __launch_bounds__(256) void k_attn(const ushort* Qb, const ushort* Kb,
                                              const ushort* Vb, ushort* AO){
  __shared__ ushort Kl[2][64][72];
  __shared__ ushort Vl[2][64][72];
  __shared__ ushort Pl[4][16][72];
  const float SCL2 = 0.125f * 1.44269504f;   // scale * log2(e)

  int qt = blockIdx.x, h = blockIdx.y, b = blockIdx.z;
  int bh = b*4 + h;
  int t = threadIdx.x, lane = t & 63, wid = t >> 6, l15 = lane & 15, g4 = lane >> 4;

  const ushort* Qg = Qb + ((size_t)bh*4096 + qt*64 + wid*16 + l15)*64 + g4*8;
  bf16x8 aq0 = *(const bf16x8*)Qg;
  bf16x8 aq1 = *(const bf16x8*)(Qg + 32);

  f32x4 oacc[4];
  #pragma unroll
  for (int m = 0; m < 4; ++m) oacc[m] = (f32x4){0.f,0.f,0.f,0.f};
  float m_s = -INFINITY, l_s = 0.f;   // per lane, q = l15 (replicated over g4)

  const ushort* Kgb = Kb + (size_t)bh*4096*64;
  const ushort* Vgb = Vb + (size_t)bh*64*4096;

  // stage tile 0
  {
    int r0 = t >> 3, seg = (t & 7)*8;
    *(uint4*)&Kl[0][r0][seg]      = *(const uint4*)(Kgb + (size_t)r0*64 + seg);
    *(uint4*)&Kl[0][r0+32][seg]   = *(const uint4*)(Kgb + (size_t)(r0+32)*64 + seg);
    *(uint4*)&Vl[0][r0][seg]      = *(const uint4*)(Vgb + (size_t)r0*4096 + seg);
    *(uint4*)&Vl[0][r0+32][seg]   = *(const uint4*)(Vgb + (size_t)(r0+32)*4096 + seg);
  }
  __syncthreads();

  for (int kb = 0; kb < 64; ++kb){
    int cur = kb & 1;
    // prefetch next tile into regs (overlaps with compute below)
    uint4 kr0, kr1, vr0, vr1;
    int r0 = t >> 3, seg = (t & 7)*8;
    if (kb < 63){
      const ushort* Kg = Kgb + (size_t)(kb+1)*64*64;
      kr0 = *(const uint4*)(Kg + (size_t)r0*64 + seg);
      kr1 = *(const uint4*)(Kg + (size_t)(r0+32)*64 + seg);
      vr0 = *(const uint4*)(Vgb + (size_t)r0*4096 + (kb+1)*64 + seg);
      vr1 = *(const uint4*)(Vgb + (size_t)(r0+32)*4096 + (kb+1)*64 + seg);
    }

    // S^T = K · Q^T :  lane holds S[q=l15][k = ct*16 + g4*4 + r]
    f32x4 s[4];
    #pragma unroll
    for (int m = 0; m < 4; ++m) s[m] = (f32x4){0.f,0.f,0.f,0.f};
    __builtin_amdgcn_s_setprio(1);
    #pragma unroll
    for (int ks = 0; ks < 2; ++ks){
      bf16x8 bq = ks ? aq1 : aq0;
      #pragma unroll
      for (int ct = 0; ct < 4; ++ct){
        bf16x8 kf = *(const bf16x8*)&Kl[cur][ct*16 + l15][ks*32 + g4*8];
        s[ct] = mfma16(kf, bq, s[ct]);
      }
    }
    __builtin_amdgcn_s_setprio(0);

    // lane-local softmax (exp2 domain), defer-max THR=8
    float vmax = s[0][0];
    #pragma unroll
    for (int ct = 0; ct < 4; ++ct)
      #pragma unroll
      for (int r = 0; r < 4; ++r) vmax = fmaxf(vmax, s[ct][r]);
    vmax = fmaxf(vmax, __shfl_xor(vmax, 16));
    vmax = fmaxf(vmax, __shfl_xor(vmax, 32));
    vmax *= SCL2;
    if (__any(vmax > m_s + 8.f)){
      float mn = fmaxf(m_s, vmax);
      float a = __builtin_amdgcn_exp2f(m_s - mn);
      m_s = mn;
      l_s *= a;
      float ar[4];
      #pragma unroll
      for (int r = 0; r < 4; ++r) ar[r] = __shfl(a, g4*4 + r);
      #pragma unroll
      for (int dt = 0; dt < 4; ++dt)
        #pragma unroll
        for (int r = 0; r < 4; ++r) oacc[dt][r] *= ar[r];
    }
    float rs = 0.f;
    float p[4][4];
    #pragma unroll
    for (int ct = 0; ct < 4; ++ct)
      #pragma unroll
      for (int r = 0; r < 4; ++r){
        float e = __builtin_amdgcn_exp2f(__builtin_fmaf(s[ct][r], SCL2, -m_s));
        p[ct][r] = e; rs += e;
      }
    rs += __shfl_xor(rs, 16);
    rs += __shfl_xor(rs, 32);
    l_s += rs;

    // P exchange through per-wave LDS (no barrier needed)
    #pragma unroll
    for (int ct = 0; ct < 4; ++ct){
      *(uint32_t*)&Pl[wid][l15][ct*16 + g4*4]     = pk2bf(p[ct][0], p[ct][1]);
      *(uint32_t*)&Pl[wid][l15][ct*16 + g4*4 + 2] = pk2bf(p[ct][2], p[ct][3]);
    }

    // PV
    __builtin_amdgcn_s_setprio(1);
    #pragma unroll
    for (int ks = 0; ks < 2; ++ks){
      bf16x8 pf = *(const bf16x8*)&Pl[wid][l15][ks*32 + g4*8];
      #pragma unroll
      for (int dt = 0; dt < 4; ++dt){
        bf16x8 vf = *(const bf16x8*)&Vl[cur][dt*16 + l15][ks*32 + g4*8];
        oacc[dt] = mfma16(pf, vf, oacc[dt]);
      }
    }
    __builtin_amdgcn_s_setprio(0);

    if (kb < 63){
      *(uint4*)&Kl[cur^1][r0][seg]    = kr0;
      *(uint4*)&Kl[cur^1][r0+32][seg] = kr1;
      *(uint4*)&Vl[cur^1][r0][seg]    = vr0;
      *(uint4*)&Vl[cur^1][r0+32][seg] = vr1;
      __syncthreads();
    }
  }

  #pragma unroll
  for (int r = 0; r < 4; ++r){
    float lr = __shfl(l_s, g4*4 + r);
    float inv = 1.f / lr;
    int n = qt*64 + wid*16 + g4*4 + r;
    ushort* dst = AO + ((size_t)b*4096 + n)*256 + h*64;
    #pragma unroll
    for (int dt = 0; dt < 4; ++dt)
      dst[dt*16 + l15] = f2bf(oacc[dt][r] * inv);
  }
}

// ---------------- proj GEMM + bias + residual ----------------
__global__ __launch_bounds__(256) void k_proj(const ushort* AO, const ushort* wpb, const float* bproj,
                                              const float* x, float* out){
  int nt = blockIdx.x, ct = blockIdx.y, b = blockIdx.z;
  int t = threadIdx.x, lane = t & 63, wid = t >> 6, l15 = lane & 15, g4 = lane >> 4;
  int o = ct*64 + wid*16 + l15;
  f32x4 acc[4];
  #pragma unroll
  for (int m = 0; m < 4; ++m) acc[m] = (f32x4){0.f,0.f,0.f,0.f};

  #pragma unroll
  for (int ks = 0; ks < 8; ++ks){
    bf16x8 bw = *(const bf16x8*)(wpb + (size_t)o*256 + ks*32 + g4*8);
    #pragma unroll
    for (int mf = 0; mf < 4; ++mf){
      int n = nt*64 + mf*16 + l15;
      bf16x8 aa = *(const bf16x8*)(AO + ((size_t)b*4096 + n)*256 + ks*32 + g4*8);
      acc[mf] = mfma16(aa, bw, acc[mf]);
    }
  }

  float bias = bproj[o];
  size_t cbase = ((size_t)b*256 + o)*4096;
  #pragma unroll
  for (int mf = 0; mf < 4; ++mf){
    int n0 = nt*64 + mf*16 + g4*4;
    f32x4 res = *(const f32x4*)(x + cbase + n0);
    f32x4 ov;
    #pragma unroll
    for (int r = 0; r < 4; ++r) ov[r] = acc[mf][r] + bias + res[r];
    *(f32x4*)(out + cbase + n0) = ov;
  }
}

extern "C" void kernel_launch(void* const* d_in, const int* in_sizes, int n_in,
                              void* d_out, int out_size, void* d_ws, size_t ws_size,
                              hipStream_t stream) {
  const float* x     = (const float*)d_in[0];
  const float* gamma = (const float*)d_in[1];
  const float* beta  = (const float*)d_in[2];
  const float* wqkv  = (const float*)d_in[3];
  const float* bqkv  = (const float*)d_in[4];
  const float* wproj = (const float*)d_in[5];
  const float* bproj = (const float*)d_in[6];
  float* out = (float*)d_out;

  char* ws = (char*)d_ws;
  float2* part   = (float2*)(ws + 0);          // 8 KB
  float2* stats  = (float2*)(ws + 8192);       // 128 B
  ushort* wq_b   = (ushort*)(ws + 16384);      // 384 KB
  ushort* wp_b   = (ushort*)(ws + 409600);     // 128 KB
  ushort* Qb     = (ushort*)(ws + 1048576);    // 4 MB  [bh][n][d]
  ushort* Kb     = (ushort*)(ws + 5242880);    // 4 MB  [bh][n][d]
  ushort* Vb     = (ushort*)(ws + 9437184);    // 4 MB  [bh][d][n]
  ushort* AO     = (ushort*)(ws + 13631488);   // 4 MB  [b][n][ci]

  k_prep<<<768, 256, 0, stream>>>(wqkv, wproj, wq_b, wp_b);
  k_gn1 <<<1024, 256, 0, stream>>>(x, part);
  k_gn2 <<<16, 64, 0, stream>>>(part, stats);
  k_qkv <<<dim3(64,12,2), 256, 0, stream>>>(x, gamma, beta, stats, wq_b, bqkv, Qb, Kb, Vb);
  k_attn<<<dim3(64,4,2), 256, 0, stream>>>(Qb, Kb, Vb, AO);
  k_proj<<<dim3(64,4,2), 256, 0, stream>>>(AO, wp_b, bproj, x, out);
}